// Round 1
// baseline (213.813 us; speedup 1.0000x reference)
//
#include <hip/hip_runtime.h>
#include <stdint.h>

typedef int i32x4 __attribute__((ext_vector_type(4)));

#define K_DIM 1024
#define BM 128
#define BN 256
#define BKK 64

// ---------------- helpers ----------------
__device__ __forceinline__ int quant1(float v, float inv) {
  float t = rintf(v * inv);                 // round half-to-even, matches jnp.round
  t = fminf(fmaxf(t, -128.0f), 127.0f);     // clip(-n-1, n)
  return (int)t;
}

__device__ __forceinline__ void gld_lds16(const signed char* g, signed char* l) {
  typedef const __attribute__((address_space(1))) unsigned int* gp_t;
  typedef __attribute__((address_space(3))) unsigned int* lp_t;
  __builtin_amdgcn_global_load_lds((gp_t)(const void*)g, (lp_t)(void*)l, 16, 0, 0);
}

// ---------------- 1) global absmax over hs ----------------
__global__ void absmax_kernel(const float* __restrict__ x, unsigned int* __restrict__ amax,
                              long long n4) {
  long long i = (long long)blockIdx.x * blockDim.x + threadIdx.x;
  const long long stride = (long long)gridDim.x * blockDim.x;
  const float4* x4 = (const float4*)x;
  float m = 0.0f;
  for (; i < n4; i += stride) {
    float4 v = x4[i];
    m = fmaxf(m, fmaxf(fmaxf(fabsf(v.x), fabsf(v.y)), fmaxf(fabsf(v.z), fabsf(v.w))));
  }
#pragma unroll
  for (int off = 32; off > 0; off >>= 1) m = fmaxf(m, __shfl_down(m, off, 64));
  __shared__ float sm[4];
  const int lane = threadIdx.x & 63, wid = threadIdx.x >> 6;
  if (lane == 0) sm[wid] = m;
  __syncthreads();
  if (threadIdx.x == 0) {
    float b = fmaxf(fmaxf(sm[0], sm[1]), fmaxf(sm[2], sm[3]));
    atomicMax(amax, __float_as_uint(b));   // all values >= 0: uint order == float order
  }
}

// ---------------- 2) per-channel weight quant + bias ----------------
__global__ void wquant_kernel(const float* __restrict__ w, const float* __restrict__ bias,
                              const unsigned int* __restrict__ amax_u,
                              signed char* __restrict__ wq,
                              float* __restrict__ bscale, float* __restrict__ bint) {
  const int o = blockIdx.x;
  const int t = threadIdx.x;
  float4 v = ((const float4*)(w + (size_t)o * K_DIM))[t];
  float m = fmaxf(fmaxf(fabsf(v.x), fabsf(v.y)), fmaxf(fabsf(v.z), fabsf(v.w)));
#pragma unroll
  for (int off = 32; off > 0; off >>= 1) m = fmaxf(m, __shfl_down(m, off, 64));
  __shared__ float sm[4];
  __shared__ float s_scale;
  const int lane = t & 63, wid = t >> 6;
  if (lane == 0) sm[wid] = m;
  __syncthreads();
  if (t == 0) {
    float wm = fmaxf(fmaxf(sm[0], sm[1]), fmaxf(sm[2], sm[3]));
    float wsc = fmaxf(wm, 1e-8f) / 127.0f;
    float asc = fmaxf(__uint_as_float(*amax_u), 1e-8f) / 127.0f;
    float bsc = wsc * asc;
    bscale[o] = bsc;
    bint[o] = rintf(bias[o] / bsc);        // b_int kept as float (unclipped, like ref)
    s_scale = wsc;
  }
  __syncthreads();
  const float inv = 1.0f / s_scale;
  int q0 = quant1(v.x, inv), q1 = quant1(v.y, inv), q2 = quant1(v.z, inv), q3 = quant1(v.w, inv);
  unsigned int p = (unsigned)(q0 & 255) | ((unsigned)(q1 & 255) << 8) |
                   ((unsigned)(q2 & 255) << 16) | ((unsigned)(q3 & 255) << 24);
  ((unsigned int*)wq)[o * 256 + t] = p;
}

// ---------------- 3) activation quant ----------------
__global__ void aquant_kernel(const float* __restrict__ x, const unsigned int* __restrict__ amax_u,
                              unsigned int* __restrict__ q4, long long n4) {
  const float asc = fmaxf(__uint_as_float(*amax_u), 1e-8f) / 127.0f;
  const float inv = 1.0f / asc;
  long long i = (long long)blockIdx.x * blockDim.x + threadIdx.x;
  const long long stride = (long long)gridDim.x * blockDim.x;
  const float4* x4 = (const float4*)x;
  for (; i < n4; i += stride) {
    float4 v = x4[i];
    int q0 = quant1(v.x, inv), q1 = quant1(v.y, inv), q2 = quant1(v.z, inv), q3 = quant1(v.w, inv);
    q4[i] = (unsigned)(q0 & 255) | ((unsigned)(q1 & 255) << 8) |
            ((unsigned)(q2 & 255) << 16) | ((unsigned)(q3 & 255) << 24);
  }
}

// ---------------- 4) int8 GEMM + fused dequant epilogue ----------------
// A[M,K] int8 row-major (x_int), W[N,K] int8 row-major (w_int, i.e. B^T)
// out[M,N] f32 = ((int32)A·W^T + b_int[n]) * bscale[n]
// LDS is FRAGMENT-ORDERED: each 16(rows)x64(k) int8 fragment = 1KB, lane-linear
// (lane l holds bytes [l*16, l*16+16) = row (l&15), k (l>>4)*16..+16).
// -> global_load_lds (lane-linear dest) needs no swizzle, ds_read_b128 conflict-free.
__global__ __launch_bounds__(256, 2) void gemm_kernel(
    const signed char* __restrict__ A, const signed char* __restrict__ W,
    const float* __restrict__ bscale, const float* __restrict__ bint,
    float* __restrict__ out, int M, int N, int K) {
  __shared__ __align__(16) signed char Alds[2][8][1024];    // 8 m-frags  (BM=128)
  __shared__ __align__(16) signed char Blds[2][16][1024];   // 16 n-frags (BN=256)

  // bijective XCD swizzle (gridDim.x % 8 == 0): each XCD gets a contiguous chunk
  const int nwg = gridDim.x;
  const int orig = blockIdx.x;
  const int wgid = (orig & 7) * (nwg >> 3) + (orig >> 3);
  const int nbn = N / BN;
  const int bm = wgid / nbn;
  const int bn = wgid % nbn;
  const int m0 = bm * BM, n0 = bn * BN;

  const int tid = threadIdx.x;
  const int lane = tid & 63;
  const int wid = tid >> 6;          // 4 waves
  const int wr = wid >> 1;           // 2 x 2 wave grid, wave tile 64x128
  const int wc = wid & 1;

  const int fr = lane & 15;          // fragment row
  const int fk = (lane >> 4) << 4;   // fragment k offset (0,16,32,48)

  // wave `wid` stages A-frags {wid, wid+4} and B-frags {wid, wid+4, wid+8, wid+12}
  const signed char* ga = A + (size_t)(m0 + wid * 16 + fr) * K + fk;
  const signed char* gb = W + (size_t)(n0 + wid * 16 + fr) * K + fk;
  const size_t rs = (size_t)64 * K;  // 64-row skip

  i32x4 acc[4][8];
#pragma unroll
  for (int i = 0; i < 4; i++)
#pragma unroll
    for (int j = 0; j < 8; j++) acc[i][j] = (i32x4){0, 0, 0, 0};

#define STAGE(buf, kof)                                         \
  do {                                                          \
    gld_lds16(ga + (kof),          &Alds[buf][wid][0]);         \
    gld_lds16(ga + (kof) + rs,     &Alds[buf][wid + 4][0]);     \
    gld_lds16(gb + (kof),          &Blds[buf][wid][0]);         \
    gld_lds16(gb + (kof) + rs,     &Blds[buf][wid + 4][0]);     \
    gld_lds16(gb + (kof) + 2 * rs, &Blds[buf][wid + 8][0]);     \
    gld_lds16(gb + (kof) + 3 * rs, &Blds[buf][wid + 12][0]);    \
  } while (0)

  STAGE(0, 0);
  asm volatile("s_waitcnt vmcnt(0)" ::: "memory");
  __syncthreads();

  const int nkt = K / BKK;  // 16
  int cur = 0;
  for (int kt = 0; kt < nkt; ++kt) {
    if (kt + 1 < nkt) STAGE(cur ^ 1, (kt + 1) * BKK);
    i32x4 af[4], bf[8];
#pragma unroll
    for (int i = 0; i < 4; i++)
      af[i] = *(const i32x4*)&Alds[cur][wr * 4 + i][lane * 16];
#pragma unroll
    for (int j = 0; j < 8; j++)
      bf[j] = *(const i32x4*)&Blds[cur][wc * 8 + j][lane * 16];
#pragma unroll
    for (int i = 0; i < 4; i++)
#pragma unroll
      for (int j = 0; j < 8; j++)
        acc[i][j] = __builtin_amdgcn_mfma_i32_16x16x64_i8(af[i], bf[j], acc[i][j], 0, 0, 0);
    __syncthreads();   // compiler drains vmcnt+lgkmcnt here (2-phase structure)
    cur ^= 1;
  }
#undef STAGE

  // epilogue: C/D layout col = lane&15, row = (lane>>4)*4 + reg  (guide §3, measured)
  const int crow0 = m0 + wr * 64;
  const int ccol0 = n0 + wc * 128;
  const int rr = (lane >> 4) * 4;
  const int cc = lane & 15;
#pragma unroll
  for (int j = 0; j < 8; j++) {
    const int col = ccol0 + j * 16 + cc;
    const float bs = bscale[col];
    const float bi = bint[col];
#pragma unroll
    for (int i = 0; i < 4; i++) {
      const int row = crow0 + i * 16 + rr;
#pragma unroll
      for (int r = 0; r < 4; r++) {
        out[(size_t)(row + r) * N + col] = ((float)acc[i][j][r] + bi) * bs;
      }
    }
  }
}

// ---------------- launch ----------------
extern "C" void kernel_launch(void* const* d_in, const int* in_sizes, int n_in,
                              void* d_out, int out_size, void* d_ws, size_t ws_size,
                              hipStream_t stream) {
  const float* hs = (const float*)d_in[0];
  const float* w = (const float*)d_in[1];
  const float* bias = (const float*)d_in[2];
  float* out = (float*)d_out;

  const long long n = (long long)in_sizes[0];     // 50331648
  const int K = K_DIM;                            // 1024
  const int O = in_sizes[2];                      // 1024
  const int M = (int)(n / K);                     // 49152

  // workspace layout (total ~49.3 MB)
  char* ws = (char*)d_ws;
  unsigned int* amax_u = (unsigned int*)ws;                        // 4 B
  float* bscale = (float*)(ws + 256);                              // 4 KB
  float* bint = (float*)(ws + 256 + 4096);                         // 4 KB
  signed char* wq = (signed char*)(ws + 65536);                    // 1 MB
  signed char* xq = (signed char*)(ws + 65536 + 1048576);          // 48 MB

  hipMemsetAsync(amax_u, 0, 4, stream);

  const long long n4 = n / 4;
  absmax_kernel<<<2048, 256, 0, stream>>>(hs, amax_u, n4);
  wquant_kernel<<<O, 256, 0, stream>>>(w, bias, amax_u, wq, bscale, bint);
  aquant_kernel<<<2048, 256, 0, stream>>>(hs, amax_u, (unsigned int*)xq, n4);

  const int nblocks = (M / BM) * (O / BN);        // 384 * 4 = 1536
  gemm_kernel<<<nblocks, 256, 0, stream>>>(xq, wq, bscale, bint, out, M, O, K);
}

// Round 2
// 200.251 us; speedup vs baseline: 1.0677x; 1.0677x over previous
//
#include <hip/hip_runtime.h>
#include <stdint.h>

typedef int i32x4 __attribute__((ext_vector_type(4)));

#define K_DIM 1024
#define BM 128
#define BN 256
#define BKK 64

// ---------------- helpers ----------------
__device__ __forceinline__ int quant1(float v, float inv) {
  float t = rintf(v * inv);                 // round half-to-even, matches jnp.round
  t = fminf(fmaxf(t, -128.0f), 127.0f);     // clip(-n-1, n)
  return (int)t;
}

__device__ __forceinline__ void gld_lds16(const signed char* g, signed char* l) {
  typedef const __attribute__((address_space(1))) unsigned int* gp_t;
  typedef __attribute__((address_space(3))) unsigned int* lp_t;
  __builtin_amdgcn_global_load_lds((gp_t)(const void*)g, (lp_t)(void*)l, 16, 0, 0);
}

// ---------------- 1) global absmax over hs ----------------
__global__ void absmax_kernel(const float* __restrict__ x, unsigned int* __restrict__ amax,
                              long long n4) {
  long long i = (long long)blockIdx.x * blockDim.x + threadIdx.x;
  const long long stride = (long long)gridDim.x * blockDim.x;
  const float4* x4 = (const float4*)x;
  float m = 0.0f;
  for (; i < n4; i += stride) {
    float4 v = x4[i];
    m = fmaxf(m, fmaxf(fmaxf(fabsf(v.x), fabsf(v.y)), fmaxf(fabsf(v.z), fabsf(v.w))));
  }
#pragma unroll
  for (int off = 32; off > 0; off >>= 1) m = fmaxf(m, __shfl_down(m, off, 64));
  __shared__ float sm[4];
  const int lane = threadIdx.x & 63, wid = threadIdx.x >> 6;
  if (lane == 0) sm[wid] = m;
  __syncthreads();
  if (threadIdx.x == 0) {
    float b = fmaxf(fmaxf(sm[0], sm[1]), fmaxf(sm[2], sm[3]));
    atomicMax(amax, __float_as_uint(b));   // all values >= 0: uint order == float order
  }
}

// ---------------- 2) per-channel weight quant + bias ----------------
__global__ void wquant_kernel(const float* __restrict__ w, const float* __restrict__ bias,
                              const unsigned int* __restrict__ amax_u,
                              signed char* __restrict__ wq,
                              float* __restrict__ bscale, float* __restrict__ bint) {
  const int o = blockIdx.x;
  const int t = threadIdx.x;
  float4 v = ((const float4*)(w + (size_t)o * K_DIM))[t];
  float m = fmaxf(fmaxf(fabsf(v.x), fabsf(v.y)), fmaxf(fabsf(v.z), fabsf(v.w)));
#pragma unroll
  for (int off = 32; off > 0; off >>= 1) m = fmaxf(m, __shfl_down(m, off, 64));
  __shared__ float sm[4];
  __shared__ float s_scale;
  const int lane = t & 63, wid = t >> 6;
  if (lane == 0) sm[wid] = m;
  __syncthreads();
  if (t == 0) {
    float wm = fmaxf(fmaxf(sm[0], sm[1]), fmaxf(sm[2], sm[3]));
    float wsc = fmaxf(wm, 1e-8f) / 127.0f;
    float asc = fmaxf(__uint_as_float(*amax_u), 1e-8f) / 127.0f;
    float bsc = wsc * asc;
    bscale[o] = bsc;
    bint[o] = rintf(bias[o] / bsc);        // b_int kept as float (unclipped, like ref)
    s_scale = wsc;
  }
  __syncthreads();
  const float inv = 1.0f / s_scale;
  int q0 = quant1(v.x, inv), q1 = quant1(v.y, inv), q2 = quant1(v.z, inv), q3 = quant1(v.w, inv);
  unsigned int p = (unsigned)(q0 & 255) | ((unsigned)(q1 & 255) << 8) |
                   ((unsigned)(q2 & 255) << 16) | ((unsigned)(q3 & 255) << 24);
  ((unsigned int*)wq)[o * 256 + t] = p;
}

// ---------------- 3) activation quant ----------------
__global__ void aquant_kernel(const float* __restrict__ x, const unsigned int* __restrict__ amax_u,
                              unsigned int* __restrict__ q4, long long n4) {
  const float asc = fmaxf(__uint_as_float(*amax_u), 1e-8f) / 127.0f;
  const float inv = 1.0f / asc;
  long long i = (long long)blockIdx.x * blockDim.x + threadIdx.x;
  const long long stride = (long long)gridDim.x * blockDim.x;
  const float4* x4 = (const float4*)x;
  for (; i < n4; i += stride) {
    float4 v = x4[i];
    int q0 = quant1(v.x, inv), q1 = quant1(v.y, inv), q2 = quant1(v.z, inv), q3 = quant1(v.w, inv);
    q4[i] = (unsigned)(q0 & 255) | ((unsigned)(q1 & 255) << 8) |
            ((unsigned)(q2 & 255) << 16) | ((unsigned)(q3 & 255) << 24);
  }
}

// ---------------- 4) int8 GEMM + fused dequant epilogue ----------------
// A[M,K] int8 row-major (x_int), W[N,K] int8 row-major (w_int, i.e. B^T)
// out[M,N] f32 = ((int32)A·W^T + b_int[n]) * bscale[n]
// LDS is FRAGMENT-ORDERED: each 16(rows)x64(k) int8 fragment = 1KB, lane-linear
// (lane l holds bytes [l*16, l*16+16) = row (l&15), k (l>>4)*16..+16).
// -> global_load_lds (lane-linear dest) needs no swizzle, ds_read_b128 conflict-free.
//
// K-loop: T3/T4 counted-vmcnt pipeline, 3 buffers, prefetch depth 2.
// Raw s_barrier + explicit vmcnt(12/6/0); never drains vmcnt to 0 mid-loop.
__global__ __launch_bounds__(256, 2) void gemm_kernel(
    const signed char* __restrict__ A, const signed char* __restrict__ W,
    const float* __restrict__ bscale, const float* __restrict__ bint,
    float* __restrict__ out, int M, int N, int K) {
  __shared__ __align__(16) signed char Alds[3][8][1024];    // 8 m-frags  (BM=128), 3 bufs
  __shared__ __align__(16) signed char Blds[3][16][1024];   // 16 n-frags (BN=256), 3 bufs

  // bijective XCD swizzle (gridDim.x % 8 == 0): each XCD gets a contiguous chunk
  const int nwg = gridDim.x;
  const int orig = blockIdx.x;
  const int wgid = (orig & 7) * (nwg >> 3) + (orig >> 3);
  const int nbn = N / BN;
  const int bm = wgid / nbn;
  const int bn = wgid % nbn;
  const int m0 = bm * BM, n0 = bn * BN;

  const int tid = threadIdx.x;
  const int lane = tid & 63;
  const int wid = tid >> 6;          // 4 waves
  const int wr = wid >> 1;           // 2 x 2 wave grid, wave tile 64x128
  const int wc = wid & 1;

  const int fr = lane & 15;          // fragment row
  const int fk = (lane >> 4) << 4;   // fragment k offset (0,16,32,48)

  // wave `wid` stages A-frags {wid, wid+4} and B-frags {wid, wid+4, wid+8, wid+12}
  const signed char* ga = A + (size_t)(m0 + wid * 16 + fr) * K + fk;
  const signed char* gb = W + (size_t)(n0 + wid * 16 + fr) * K + fk;
  const size_t rs = (size_t)64 * K;  // 64-row skip

  i32x4 acc[4][8];
#pragma unroll
  for (int i = 0; i < 4; i++)
#pragma unroll
    for (int j = 0; j < 8; j++) acc[i][j] = (i32x4){0, 0, 0, 0};

#define STAGE(buf, kof)                                         \
  do {                                                          \
    gld_lds16(ga + (kof),          &Alds[buf][wid][0]);         \
    gld_lds16(ga + (kof) + rs,     &Alds[buf][wid + 4][0]);     \
    gld_lds16(gb + (kof),          &Blds[buf][wid][0]);         \
    gld_lds16(gb + (kof) + rs,     &Blds[buf][wid + 4][0]);     \
    gld_lds16(gb + (kof) + 2 * rs, &Blds[buf][wid + 8][0]);     \
    gld_lds16(gb + (kof) + 3 * rs, &Blds[buf][wid + 12][0]);    \
  } while (0)

// BODY: wait for buf cur's 6 loads (counted, oldest-first), barrier, ds_read,
// lgkmcnt(0)+barrier (all waves' reads done -> buf may be overwritten), MFMA.
#define BODY(cur, WAITIMM)                                              \
  do {                                                                  \
    asm volatile("s_waitcnt vmcnt(" #WAITIMM ")" ::: "memory");         \
    __builtin_amdgcn_sched_barrier(0);                                  \
    __builtin_amdgcn_s_barrier();                                       \
    __builtin_amdgcn_sched_barrier(0);                                  \
    i32x4 af[4], bf[8];                                                 \
    _Pragma("unroll")                                                   \
    for (int i = 0; i < 4; i++)                                         \
      af[i] = *(const i32x4*)&Alds[cur][wr * 4 + i][lane * 16];         \
    _Pragma("unroll")                                                   \
    for (int j = 0; j < 8; j++)                                         \
      bf[j] = *(const i32x4*)&Blds[cur][wc * 8 + j][lane * 16];         \
    asm volatile("s_waitcnt lgkmcnt(0)" ::: "memory");                  \
    __builtin_amdgcn_sched_barrier(0);                                  \
    __builtin_amdgcn_s_barrier();                                       \
    __builtin_amdgcn_sched_barrier(0);                                  \
    __builtin_amdgcn_s_setprio(1);                                      \
    _Pragma("unroll")                                                   \
    for (int i = 0; i < 4; i++)                                         \
      _Pragma("unroll")                                                 \
      for (int j = 0; j < 8; j++)                                       \
        acc[i][j] = __builtin_amdgcn_mfma_i32_16x16x64_i8(af[i], bf[j], acc[i][j], 0, 0, 0); \
    __builtin_amdgcn_s_setprio(0);                                      \
  } while (0)

  const int nkt = K / BKK;  // 16
  // prologue: 2 tiles in flight
  STAGE(0, 0);
  STAGE(1, BKK);
  int cur = 0;
  for (int kt = 0; kt < nkt - 2; ++kt) {
    const int nx2 = cur + 2 >= 3 ? cur - 1 : cur + 2;
    STAGE(nx2, (kt + 2) * BKK);      // 18 outstanding after issue
    BODY(cur, 12);                   // tile kt's 6 landed
    cur = cur + 1 >= 3 ? 0 : cur + 1;
  }
  BODY(cur, 6);                      // tile nkt-2 (12 outstanding -> 6)
  cur = cur + 1 >= 3 ? 0 : cur + 1;
  BODY(cur, 0);                      // tile nkt-1 (drain)
#undef BODY
#undef STAGE

  // epilogue: C/D layout col = lane&15, row = (lane>>4)*4 + reg  (guide §3, measured)
  const int crow0 = m0 + wr * 64;
  const int ccol0 = n0 + wc * 128;
  const int rr = (lane >> 4) * 4;
  const int cc = lane & 15;
#pragma unroll
  for (int j = 0; j < 8; j++) {
    const int col = ccol0 + j * 16 + cc;
    const float bs = bscale[col];
    const float bi = bint[col];
#pragma unroll
    for (int i = 0; i < 4; i++) {
      const int row = crow0 + i * 16 + rr;
#pragma unroll
      for (int r = 0; r < 4; r++) {
        __builtin_nontemporal_store(((float)acc[i][j][r] + bi) * bs,
                                    &out[(size_t)(row + r) * N + col]);
      }
    }
  }
}

// ---------------- launch ----------------
extern "C" void kernel_launch(void* const* d_in, const int* in_sizes, int n_in,
                              void* d_out, int out_size, void* d_ws, size_t ws_size,
                              hipStream_t stream) {
  const float* hs = (const float*)d_in[0];
  const float* w = (const float*)d_in[1];
  const float* bias = (const float*)d_in[2];
  float* out = (float*)d_out;

  const long long n = (long long)in_sizes[0];     // 50331648
  const int K = K_DIM;                            // 1024
  const int O = in_sizes[2];                      // 1024
  const int M = (int)(n / K);                     // 49152

  // workspace layout (total ~49.3 MB)
  char* ws = (char*)d_ws;
  unsigned int* amax_u = (unsigned int*)ws;                        // 4 B
  float* bscale = (float*)(ws + 256);                              // 4 KB
  float* bint = (float*)(ws + 256 + 4096);                         // 4 KB
  signed char* wq = (signed char*)(ws + 65536);                    // 1 MB
  signed char* xq = (signed char*)(ws + 65536 + 1048576);          // 48 MB

  hipMemsetAsync(amax_u, 0, 4, stream);

  const long long n4 = n / 4;
  absmax_kernel<<<2048, 256, 0, stream>>>(hs, amax_u, n4);
  wquant_kernel<<<O, 256, 0, stream>>>(w, bias, amax_u, wq, bscale, bint);
  aquant_kernel<<<2048, 256, 0, stream>>>(hs, amax_u, (unsigned int*)xq, n4);

  const int nblocks = (M / BM) * (O / BN);        // 384 * 4 = 1536
  gemm_kernel<<<nblocks, 256, 0, stream>>>(xq, wq, bscale, bint, out, M, O, K);
}